// Round 1
// 91.128 us; speedup vs baseline: 1.0143x; 1.0143x over previous
//
#include <hip/hip_runtime.h>

namespace {
constexpr int Bsz = 32;
constexpr int Ssz = 128;
constexpr int Hsz = 768;
constexpr int Msz = 8;     // max span width
constexpr int MHs = 6;     // holder max width
constexpr int NSPAN = Msz * Ssz; // 1024
}

__device__ __forceinline__ bool gtpair(float av, int ai, float bv, int bi) {
    // strict "ranks higher": greater value, or equal value with lower index (stable)
    return (av > bv) || (av == bv && ai < bi);
}

struct Top4 { float v[4]; int ix[4]; };

__device__ __forceinline__ void t4_init(Top4& t) {
#pragma unroll
    for (int k = 0; k < 4; ++k) { t.v[k] = -3.f; t.ix[k] = 0x7fffffff; }
}

// Static-index insert: candidate (cv,ci) into sorted-descending list.
// Pure compare+select — no dynamic array subscripts (avoids scratch).
__device__ __forceinline__ void t4_insert_g(Top4& a, float cv, int ci) {
    bool g0 = gtpair(cv, ci, a.v[0], a.ix[0]);
    bool g1 = gtpair(cv, ci, a.v[1], a.ix[1]);
    bool g2 = gtpair(cv, ci, a.v[2], a.ix[2]);
    bool g3 = gtpair(cv, ci, a.v[3], a.ix[3]);
    float nv3 = g2 ? a.v[2]  : (g3 ? cv : a.v[3]);
    int   ni3 = g2 ? a.ix[2] : (g3 ? ci : a.ix[3]);
    float nv2 = g1 ? a.v[1]  : (g2 ? cv : a.v[2]);
    int   ni2 = g1 ? a.ix[1] : (g2 ? ci : a.ix[2]);
    float nv1 = g0 ? a.v[0]  : (g1 ? cv : a.v[1]);
    int   ni1 = g0 ? a.ix[0] : (g1 ? ci : a.ix[1]);
    float nv0 = g0 ? cv : a.v[0];
    int   ni0 = g0 ? ci : a.ix[0];
    a.v[0] = nv0; a.ix[0] = ni0;
    a.v[1] = nv1; a.ix[1] = ni1;
    a.v[2] = nv2; a.ix[2] = ni2;
    a.v[3] = nv3; a.ix[3] = ni3;
}

// Merge sorted-descending b into a by rank-order insertion (static indices only).
__device__ __forceinline__ void t4_merge_into(Top4& a, const Top4& b) {
#pragma unroll
    for (int k = 0; k < 4; ++k) t4_insert_g(a, b.v[k], b.ix[k]);
}

__device__ __forceinline__ Top4 t4_wave_merge(Top4 t) {
#pragma unroll
    for (int off = 1; off < 64; off <<= 1) {
        Top4 o;
#pragma unroll
        for (int k = 0; k < 4; ++k) {
            o.v[k]  = __shfl_xor(t.v[k], off);
            o.ix[k] = __shfl_xor(t.ix[k], off);
        }
        t4_merge_into(t, o);
    }
    return t;
}

// K1: dh[row] = emb[row,:]·wh, dt[row] = emb[row,:]·wt
// 2 rows per wave (6 independent load streams), grid 512 x 4 waves = 1024 rows x2.
// Unchanged: 512 blocks pull the cold 12.6 MB emb at full-chip HBM BW (~2-4 us);
// a fused 32-block variant would throttle this read to ~1/8 of chip BW.
__global__ __launch_bounds__(256) void row_dots_kernel(
    const float* __restrict__ emb, const float* __restrict__ wh,
    const float* __restrict__ wt, float* __restrict__ dh, float* __restrict__ dt)
{
    int wave = blockIdx.x * 4 + (threadIdx.x >> 6);   // 0..2047
    int lane = threadIdx.x & 63;
    int row0 = wave * 2;

    const float4* wh4 = (const float4*)wh;
    const float4* wt4 = (const float4*)wt;
    float4 WH0 = wh4[lane], WH1 = wh4[lane + 64], WH2 = wh4[lane + 128];
    float4 WT0 = wt4[lane], WT1 = wt4[lane + 64], WT2 = wt4[lane + 128];

    const float4* r0 = (const float4*)(emb + (size_t)row0 * Hsz);
    const float4* r1 = r0 + (Hsz / 4);
    float4 a0 = r0[lane], a1 = r0[lane + 64], a2 = r0[lane + 128];
    float4 b0 = r1[lane], b1 = r1[lane + 64], b2 = r1[lane + 128];

    float ph0 = 0.f, pt0 = 0.f, ph1 = 0.f, pt1 = 0.f;
    ph0 = fmaf(a0.x, WH0.x, fmaf(a0.y, WH0.y, fmaf(a0.z, WH0.z, fmaf(a0.w, WH0.w, ph0))));
    ph0 = fmaf(a1.x, WH1.x, fmaf(a1.y, WH1.y, fmaf(a1.z, WH1.z, fmaf(a1.w, WH1.w, ph0))));
    ph0 = fmaf(a2.x, WH2.x, fmaf(a2.y, WH2.y, fmaf(a2.z, WH2.z, fmaf(a2.w, WH2.w, ph0))));
    pt0 = fmaf(a0.x, WT0.x, fmaf(a0.y, WT0.y, fmaf(a0.z, WT0.z, fmaf(a0.w, WT0.w, pt0))));
    pt0 = fmaf(a1.x, WT1.x, fmaf(a1.y, WT1.y, fmaf(a1.z, WT1.z, fmaf(a1.w, WT1.w, pt0))));
    pt0 = fmaf(a2.x, WT2.x, fmaf(a2.y, WT2.y, fmaf(a2.z, WT2.z, fmaf(a2.w, WT2.w, pt0))));
    ph1 = fmaf(b0.x, WH0.x, fmaf(b0.y, WH0.y, fmaf(b0.z, WH0.z, fmaf(b0.w, WH0.w, ph1))));
    ph1 = fmaf(b1.x, WH1.x, fmaf(b1.y, WH1.y, fmaf(b1.z, WH1.z, fmaf(b1.w, WH1.w, ph1))));
    ph1 = fmaf(b2.x, WH2.x, fmaf(b2.y, WH2.y, fmaf(b2.z, WH2.z, fmaf(b2.w, WH2.w, ph1))));
    pt1 = fmaf(b0.x, WT0.x, fmaf(b0.y, WT0.y, fmaf(b0.z, WT0.z, fmaf(b0.w, WT0.w, pt1))));
    pt1 = fmaf(b1.x, WT1.x, fmaf(b1.y, WT1.y, fmaf(b1.z, WT1.z, fmaf(b1.w, WT1.w, pt1))));
    pt1 = fmaf(b2.x, WT2.x, fmaf(b2.y, WT2.y, fmaf(b2.z, WT2.z, fmaf(b2.w, WT2.w, pt1))));

#pragma unroll
    for (int off = 32; off; off >>= 1) {
        ph0 += __shfl_down(ph0, off);
        pt0 += __shfl_down(pt0, off);
        ph1 += __shfl_down(ph1, off);
        pt1 += __shfl_down(pt1, off);
    }
    if (lane == 0) {
        dh[row0] = ph0; dt[row0] = pt0;
        dh[row0 + 1] = ph1; dt[row0 + 1] = pt1;
    }
}

// K2: one block per batch — scores, static-network top-4, batched-load projections.
// This round: (a) wi/we staged global->reg (issued right after barrier 1, landing
// under phase-1 VALU work) ->LDS with stride-5 float4 padding (64B lane stride
// would be a 32-way bank conflict; stride-80B covers all 32 banks per 8 lanes);
// (b) both projection slots (target+holder) gathered/accumulated in ONE
// branchless pass: one emb-latency window instead of two, one 12-value
// shuffle reduce instead of two 8-value ones.
__global__ __launch_bounds__(256) void per_batch_kernel(
    const float* __restrict__ emb, const int* __restrict__ mask,
    const float* __restrict__ bh_p, const float* __restrict__ bt_p,
    const float* __restrict__ wi, const float* __restrict__ bi,
    const float* __restrict__ we, const float* __restrict__ be,
    const float* __restrict__ dh, const float* __restrict__ dt,
    float* __restrict__ out)
{
    const int b = blockIdx.x;
    const int tid = threadIdx.x;
    const int wavei = tid >> 6, lane = tid & 63;

    __shared__ float dsh[Ssz], dst_[Ssz];
    __shared__ int   len_s;
    __shared__ float swv[4][4];
    __shared__ int   swi[4][4];
    __shared__ int   sel[8];       // 0..3 targets, 4..7 holders
    __shared__ int   val[8];
    __shared__ float proj[8][8];
    // Padded weight staging: float4 row-group j (4 consecutive float4 = 64B)
    // lives at slots [5j .. 5j+3], slot 5j+4 is pad. Read stride per lane is
    // 80B -> bank starts cycle through all 32 banks every 8 lanes (conflict-free
    // throughput); unpadded 64B stride would alias 32 lanes onto 4 banks.
    __shared__ float4 wi_s[(Hsz / 4) * 5];      // 960 f4 = 15 KB
    __shared__ float4 we_s[(2 * Hsz / 4) * 5];  // 1920 f4 = 30 KB

    // phase 0: per-row dots into LDS; wave0 computes sentence length
    if (tid < Ssz) {
        dsh[tid]  = dh[b * Ssz + tid];
        dst_[tid] = dt[b * Ssz + tid];
    }
    if (wavei == 0) {
        int m = mask[b * Ssz + lane] + mask[b * Ssz + lane + 64];
#pragma unroll
        for (int off = 32; off; off >>= 1) m += __shfl_down(m, off);
        if (lane == 0) len_s = m;
    }
    __syncthreads();                                        // barrier 1

    // issue the 36 KB weight stream NOW (independent of selection); the loads
    // land under phase-1's ~1.2 us of VALU work instead of sitting as a cold
    // latency window on phase-2's critical path. (After barrier 1, so the
    // implicit vmcnt(0) drain of barrier 1 doesn't stall on them.)
    const float4* wi4g = (const float4*)wi;     // 768 float4
    const float4* we4g = (const float4*)we;     // 1536 float4
    float4 wreg0 = wi4g[tid];
    float4 wreg1 = wi4g[tid + 256];
    float4 wreg2 = wi4g[tid + 512];
    float4 wreg3 = we4g[tid];
    float4 wreg4 = we4g[tid + 256];
    float4 wreg5 = we4g[tid + 512];
    float4 wreg6 = we4g[tid + 768];
    float4 wreg7 = we4g[tid + 1024];
    float4 wreg8 = we4g[tid + 1280];

    const int   len = len_s;
    const float bhv = bh_p[0], btv = bt_p[0];
    float* out_impl = out;                                  // [B,4,4]
    float* out_expl = out + Bsz * 16;                       // [B,16,4]
    float* out_hs   = out_expl + Bsz * 64;                  // [B,1024]
    float* out_ts   = out_hs + Bsz * NSPAN;                 // [B,1024]

    // phase 1: thread = (start, grp); grp 0 (waves 0-1) = targets,
    // grp 1 (waves 2-3) = holders. Running sum over widths 1..8; candidates
    // generated in ascending span index (stable: insert_g keeps lower index on tie).
    {
        const int st  = tid & (Ssz - 1);
        const int grp = tid >> 7;
        const float* dar = grp ? dsh : dst_;
        const float  bv  = grp ? bhv : btv;
        float* outp = grp ? (out_hs + b * NSPAN) : (out_ts + b * NSPAN);
        Top4 t4l; t4_init(t4l);
        float run = 0.f;
#pragma unroll
        for (int widx = 0; widx < Msz; ++widx) {
            bool fits = (st < len - widx);
            if (fits) run += dar[st + widx];       // st+widx < len <= Ssz, in-bounds
            bool valid = fits && (grp == 0 || widx < MHs);
            float sc = -1.f;
            if (valid) {
                float x = run * (1.f / (float)(widx + 1)) + bv;
                sc = 1.f / (1.f + __expf(-x));
            }
            int i = (widx << 7) | st;
            outp[i] = sc;
            t4_insert_g(t4l, sc, i);
        }
        t4l = t4_wave_merge(t4l);
        if (lane == 0) {
#pragma unroll
            for (int k = 0; k < 4; ++k) { swv[wavei][k] = t4l.v[k]; swi[wavei][k] = t4l.ix[k]; }
        }
    }

    // scatter staged weights into padded LDS (write-late half of the T14 split;
    // global loads have drained by now, ds_writes are covered by barrier 2)
    {
        int i0 = tid;
        wi_s[5 * (i0 >> 2) + (i0 & 3)] = wreg0;
        int i1 = tid + 256;
        wi_s[5 * (i1 >> 2) + (i1 & 3)] = wreg1;
        int i2 = tid + 512;
        wi_s[5 * (i2 >> 2) + (i2 & 3)] = wreg2;
        int j0 = tid;
        we_s[5 * (j0 >> 2) + (j0 & 3)] = wreg3;
        int j1 = tid + 256;
        we_s[5 * (j1 >> 2) + (j1 & 3)] = wreg4;
        int j2 = tid + 512;
        we_s[5 * (j2 >> 2) + (j2 & 3)] = wreg5;
        int j3 = tid + 768;
        we_s[5 * (j3 >> 2) + (j3 & 3)] = wreg6;
        int j4 = tid + 1024;
        we_s[5 * (j4 >> 2) + (j4 & 3)] = wreg7;
        int j5 = tid + 1280;
        we_s[5 * (j5 >> 2) + (j5 & 3)] = wreg8;
    }
    __syncthreads();                                        // barrier 2

    // cross-wave merge: tid 0 -> targets (waves 0,1 -> slots 0..3),
    //                   tid 1 -> holders (waves 2,3 -> slots 4..7)
    if (tid < 2) {
        Top4 a, c;
#pragma unroll
        for (int k = 0; k < 4; ++k) {
            a.v[k] = swv[2 * tid][k];     a.ix[k] = swi[2 * tid][k];
            c.v[k] = swv[2 * tid + 1][k]; c.ix[k] = swi[2 * tid + 1][k];
        }
        t4_merge_into(a, c);
#pragma unroll
        for (int k = 0; k < 4; ++k) {
            sel[tid * 4 + k] = a.ix[k];
            val[tid * 4 + k] = (a.v[k] > 0.f) ? 1 : 0;
        }
    }
    __syncthreads();                                        // barrier 3

    // phase 2: each wave handles target slot `wavei` AND holder slot `wavei+4`
    // in one branchless pass. All 48 emb float4 loads issue as one batch (one
    // L3-latency window); weights come from padded LDS. Validity folded into
    // zero multipliers + clamped addresses (a selected invalid span can have
    // st+w beyond the sentence; clamp keeps the gather in-bounds, phase 3
    // gates the result by val[] as before).
    {
        const int tIdx = sel[wavei],    hIdx = sel[wavei + 4];
        const int tvld = val[wavei],    hvld = val[wavei + 4];
        const int tw = (tIdx >> 7) + 1, tst = tIdx & (Ssz - 1);
        const int hw = (hIdx >> 7) + 1, hst = hIdx & (Ssz - 1);
        const int   gtw  = tvld ? tw : 1;
        const int   gtst = tvld ? tst : 0;
        const int   ghw  = hvld ? hw : 1;
        const int   ghst = hvld ? hst : 0;
        const float tinv = tvld ? (1.f / (float)tw) : 0.f;
        const float hinv = hvld ? (1.f / (float)hw) : 0.f;
        const float4* tbase = (const float4*)(emb + ((size_t)b * Ssz + gtst) * Hsz);
        const float4* hbase = (const float4*)(emb + ((size_t)b * Ssz + ghst) * Hsz);

        float4 t0 = {0,0,0,0}, t1 = {0,0,0,0}, t2 = {0,0,0,0};
        float4 h0 = {0,0,0,0}, h1 = {0,0,0,0}, h2 = {0,0,0,0};
#pragma unroll
        for (int r = 0; r < Msz; ++r) {
            int   trr = (r < gtw) ? r : (gtw - 1);          // clamped: always valid row
            float tm  = (r < gtw) ? tinv : 0.f;
            int   hrr = (r < ghw) ? r : (ghw - 1);
            float hm  = (r < ghw) ? hinv : 0.f;
            const float4* trp = tbase + trr * (Hsz / 4);
            const float4* hrp = hbase + hrr * (Hsz / 4);
            float4 a0 = trp[lane], a1 = trp[lane + 64], a2 = trp[lane + 128];
            float4 c0 = hrp[lane], c1 = hrp[lane + 64], c2 = hrp[lane + 128];
            t0.x = fmaf(a0.x, tm, t0.x); t0.y = fmaf(a0.y, tm, t0.y);
            t0.z = fmaf(a0.z, tm, t0.z); t0.w = fmaf(a0.w, tm, t0.w);
            t1.x = fmaf(a1.x, tm, t1.x); t1.y = fmaf(a1.y, tm, t1.y);
            t1.z = fmaf(a1.z, tm, t1.z); t1.w = fmaf(a1.w, tm, t1.w);
            t2.x = fmaf(a2.x, tm, t2.x); t2.y = fmaf(a2.y, tm, t2.y);
            t2.z = fmaf(a2.z, tm, t2.z); t2.w = fmaf(a2.w, tm, t2.w);
            h0.x = fmaf(c0.x, hm, h0.x); h0.y = fmaf(c0.y, hm, h0.y);
            h0.z = fmaf(c0.z, hm, h0.z); h0.w = fmaf(c0.w, hm, h0.w);
            h1.x = fmaf(c1.x, hm, h1.x); h1.y = fmaf(c1.y, hm, h1.y);
            h1.z = fmaf(c1.z, hm, h1.z); h1.w = fmaf(c1.w, hm, h1.w);
            h2.x = fmaf(c2.x, hm, h2.x); h2.y = fmaf(c2.y, hm, h2.y);
            h2.z = fmaf(c2.z, hm, h2.z); h2.w = fmaf(c2.w, hm, h2.w);
        }

        // weight FMAs from padded LDS:
        //   acc[0..3]  = target rep · wi            (implicit logits)
        //   acc[4..7]  = target rep · we[H:2H]      (explicit, bottom half)
        //   acc[8..11] = holder rep · we[0:H]       (explicit, top half)
        float acc[12] = {0,0,0,0,0,0,0,0,0,0,0,0};
#pragma unroll
        for (int ii = 0; ii < 3; ++ii) {
            float4 trep = (ii == 0) ? t0 : ((ii == 1) ? t1 : t2);
            float4 hrep = (ii == 0) ? h0 : ((ii == 1) ? h1 : h2);
            float tr[4] = {trep.x, trep.y, trep.z, trep.w};
            float hr[4] = {hrep.x, hrep.y, hrep.z, hrep.w};
            int j = lane + 64 * ii;                          // row-group 0..191
#pragma unroll
            for (int t = 0; t < 4; ++t) {
                float4 a  = wi_s[5 * j + t];                 // wi rows 4j..4j+3
                float4 cb = we_s[5 * (j + Hsz / 4) + t];     // we bottom-half rows
                float4 ct = we_s[5 * j + t];                 // we top-half rows
                float rt = tr[t], rh = hr[t];
                acc[0] = fmaf(rt, a.x,  acc[0]); acc[1] = fmaf(rt, a.y,  acc[1]);
                acc[2] = fmaf(rt, a.z,  acc[2]); acc[3] = fmaf(rt, a.w,  acc[3]);
                acc[4] = fmaf(rt, cb.x, acc[4]); acc[5] = fmaf(rt, cb.y, acc[5]);
                acc[6] = fmaf(rt, cb.z, acc[6]); acc[7] = fmaf(rt, cb.w, acc[7]);
                acc[8]  = fmaf(rh, ct.x, acc[8]);  acc[9]  = fmaf(rh, ct.y, acc[9]);
                acc[10] = fmaf(rh, ct.z, acc[10]); acc[11] = fmaf(rh, ct.w, acc[11]);
            }
        }

#pragma unroll
        for (int off = 32; off; off >>= 1)
#pragma unroll
            for (int c = 0; c < 12; ++c) acc[c] += __shfl_down(acc[c], off);
        if (lane == 0) {
#pragma unroll
            for (int c = 0; c < 8; ++c) proj[wavei][c] = acc[c];
#pragma unroll
            for (int c = 0; c < 4; ++c) proj[wavei + 4][c] = acc[8 + c];
        }
    }
    __syncthreads();                                        // barrier 4

    // phase 3: final logits
    if (tid < 16) {                 // implicit: [4 targets][4 cols]
        int k = tid >> 2, c = tid & 3;
        out_impl[b * 16 + tid] = bi[c] + (val[k] ? proj[k][c] : 0.f);
    } else if (tid >= 64 && tid < 128) {  // explicit: [4 holders][4 targets][4 cols]
        int u = tid - 64;
        int j = u >> 4, k = (u >> 2) & 3, c = u & 3;
        float v = be[c];
        if (val[4 + j] && val[k]) v += proj[4 + j][c] + proj[k][4 + c];
        out_expl[b * 64 + u] = v;
    }
}

extern "C" void kernel_launch(void* const* d_in, const int* in_sizes, int n_in,
                              void* d_out, int out_size, void* d_ws, size_t ws_size,
                              hipStream_t stream) {
    const float* emb  = (const float*)d_in[0];
    const int*   mask = (const int*)d_in[1];
    const float* wh   = (const float*)d_in[2];
    const float* bh   = (const float*)d_in[3];
    const float* wt   = (const float*)d_in[4];
    const float* bt   = (const float*)d_in[5];
    const float* wi   = (const float*)d_in[6];
    const float* bi   = (const float*)d_in[7];
    const float* we   = (const float*)d_in[8];
    const float* be   = (const float*)d_in[9];
    float* out = (float*)d_out;

    float* dh = (float*)d_ws;           // [B*S]
    float* dt = dh + Bsz * Ssz;         // [B*S]

    // 512 blocks x 4 waves x 2 rows = 4096 rows (B*S)
    row_dots_kernel<<<512, 256, 0, stream>>>(emb, wh, wt, dh, dt);
    per_batch_kernel<<<Bsz, 256, 0, stream>>>(emb, mask, bh, bt, wi, bi, we, be,
                                              dh, dt, out);
}